// Round 9
// baseline (279.128 us; speedup 1.0000x reference)
//
#include <hip/hip_runtime.h>
#include <hip/hip_bf16.h>

#define DIM 256
#define BATCH 8
#define SEQ 4096
#define MTOT (BATCH*SEQ)
#define NSPLIT 8   // kv split-K factor (512 l per split)

typedef __attribute__((ext_vector_type(8))) short bf16x8;
typedef __attribute__((ext_vector_type(4))) float f32x4;
typedef __attribute__((ext_vector_type(8))) unsigned short u16x8;
typedef __attribute__((ext_vector_type(4))) unsigned short u16x4;

__device__ inline unsigned short f2b(float f){
  unsigned int u = __float_as_uint(f);
  u = u + 0x7FFFu + ((u >> 16) & 1u);   // RNE
  return (unsigned short)(u >> 16);
}
__device__ inline float b2f(unsigned short h){
  return __uint_as_float(((unsigned int)h) << 16);
}

// ---------------------------------------------------------------------------
// Direct-from-global MFMA fragment loads — NO LDS, NO barriers.
// mfma_f32_16x16x32_bf16 A/B frag layout (m89): row = lane&15, k = (lane>>4)*8+j.
// A frag-load instruction = 16 rows x 64 B contiguous -> cacheline-coalesced.
// ---------------------------------------------------------------------------
__device__ inline bf16x8 ldfrag_b(const unsigned short* base, long row0, int ld, int k0, int lane){
  return *(const bf16x8*)(base + (row0 + (lane & 15))*(long)ld + k0 + ((lane >> 4) << 3));
}
__device__ inline bf16x8 ldfrag_f(const float* base, long row0, int ld, int k0, int lane){
  const float* p = base + (row0 + (lane & 15))*(long)ld + k0 + ((lane >> 4) << 3);
  f32x4 lo = *(const f32x4*)p;
  f32x4 hi = *(const f32x4*)(p + 4);
  bf16x8 r;
  r[0] = (short)f2b(lo[0]); r[1] = (short)f2b(lo[1]);
  r[2] = (short)f2b(lo[2]); r[3] = (short)f2b(lo[3]);
  r[4] = (short)f2b(hi[0]); r[5] = (short)f2b(hi[1]);
  r[6] = (short)f2b(hi[2]); r[7] = (short)f2b(hi[3]);
  return r;
}

// Wt[s][n][k] = Ws[k][n]  (bf16, B^T layout; s: 0=Wq 1=Wk 2=Wv)
__global__ __launch_bounds__(256) void prep_wt(const float* __restrict__ Wq, const float* __restrict__ Wk,
                                               const float* __restrict__ Wv, unsigned short* __restrict__ Wt){
  int i = blockIdx.x*256 + threadIdx.x;
  int s = i >> 16, r = i & 65535, n = r & 255, kk = r >> 8;
  const float* W = (s == 0) ? Wq : ((s == 1) ? Wk : Wv);
  Wt[s*65536 + n*256 + kk] = f2b(W[kk*256 + n]);
}

// All three projections. grid (lt 0..31, dt 0..1, bz 0..23): sel=bz%3 (0=K,1=V,2=Q), b=bz/3.
// sel 0/1: out[d][l] tile: A = Wt_s (rows=d_out), B = X (rows=l)  -> Kt/Vt transposed
// sel 2:   out[l][d] tile: A = X (rows=l),       B = Wt_q (rows=d_out) -> Q natural
__global__ __launch_bounds__(256) void proj_all_ker(const float* __restrict__ qin, const float* __restrict__ kin,
                                                    const float* __restrict__ vin,
                                                    const unsigned short* __restrict__ Wt,
                                                    const float* __restrict__ bqp, const float* __restrict__ bkp,
                                                    const float* __restrict__ bvp,
                                                    unsigned short* __restrict__ Qo,
                                                    unsigned short* __restrict__ Kt, unsigned short* __restrict__ Vt,
                                                    float* __restrict__ ksum){
  int lt = blockIdx.x, dt = blockIdx.y;
  int bz = blockIdx.z, sel = bz % 3, b = bz / 3;
  int tid = threadIdx.x, lane = tid & 63, w = tid >> 6, wr = w >> 1, wc = w & 1;

  const float* X = (sel == 0 ? kin : (sel == 1 ? vin : qin)) + ((long)b*SEQ + (long)lt*128)*DIM;
  const unsigned short* Wb = Wt + ((sel + 1) % 3)*DIM*DIM + dt*128*DIM;   // K->Wk, V->Wv, Q->Wq
  const float* bias = (sel == 0 ? bkp : (sel == 1 ? bvp : bqp));

  f32x4 acc[4][4] = {};
  if (sel == 2){
    #pragma unroll
    for (int ks = 0; ks < 8; ks++){
      int k0 = ks*32;
      bf16x8 af[4], bf[4];
      #pragma unroll
      for (int m = 0; m < 4; m++) af[m] = ldfrag_f(X , wr*64 + m*16, DIM, k0, lane);
      #pragma unroll
      for (int n = 0; n < 4; n++) bf[n] = ldfrag_b(Wb, wc*64 + n*16, DIM, k0, lane);
      #pragma unroll
      for (int m = 0; m < 4; m++)
        #pragma unroll
        for (int n = 0; n < 4; n++)
          acc[m][n] = __builtin_amdgcn_mfma_f32_16x16x32_bf16(af[m], bf[n], acc[m][n], 0, 0, 0);
    }
  } else {
    #pragma unroll
    for (int ks = 0; ks < 8; ks++){
      int k0 = ks*32;
      bf16x8 af[4], bf[4];
      #pragma unroll
      for (int m = 0; m < 4; m++) af[m] = ldfrag_b(Wb, wr*64 + m*16, DIM, k0, lane);
      #pragma unroll
      for (int n = 0; n < 4; n++) bf[n] = ldfrag_f(X , wc*64 + n*16, DIM, k0, lane);
      #pragma unroll
      for (int m = 0; m < 4; m++)
        #pragma unroll
        for (int n = 0; n < 4; n++)
          acc[m][n] = __builtin_amdgcn_mfma_f32_16x16x32_bf16(af[m], bf[n], acc[m][n], 0, 0, 0);
    }
  }

  int r0 = lane & 15, rg = lane >> 4;

  if (sel == 2){
    // acc rows = l, cols = d_out
    #pragma unroll
    for (int n = 0; n < 4; n++){
      int col = dt*128 + wc*64 + n*16 + r0;
      float bv = bias[col];
      #pragma unroll
      for (int m = 0; m < 4; m++)
        #pragma unroll
        for (int r = 0; r < 4; r++){
          long row = (long)b*SEQ + lt*128 + wr*64 + m*16 + rg*4 + r;
          float vv = acc[m][n][r] + bv;
          vv = vv > 0.f ? vv + 1.f : expf(vv);   // elu+1
          Qo[row*DIM + col] = f2b(vv);
        }
    }
    return;
  }

  // sel 0/1: acc rows = d_out, cols = l  (transposed outputs Kt/Vt)
  unsigned short* Yt = (sel == 1 ? Vt : Kt) + (long)b*DIM*SEQ;
  float sums[4][4];
  #pragma unroll
  for (int m = 0; m < 4; m++) for (int r = 0; r < 4; r++) sums[m][r] = 0.f;
  #pragma unroll
  for (int m = 0; m < 4; m++)
    #pragma unroll
    for (int r = 0; r < 4; r++){
      int row = dt*128 + wr*64 + m*16 + rg*4 + r;
      float bvv = bias[row];
      #pragma unroll
      for (int n = 0; n < 4; n++){
        int col = lt*128 + wc*64 + n*16 + r0;
        float vv = acc[m][n][r] + bvv;
        if (sel == 0) vv = vv > 0.f ? vv + 1.f : expf(vv);
        Yt[(long)row*SEQ + col] = f2b(vv);
        sums[m][r] += vv;
      }
    }
  if (sel == 0){
    #pragma unroll
    for (int m = 0; m < 4; m++)
      #pragma unroll
      for (int r = 0; r < 4; r++){
        float s = sums[m][r];
        s += __shfl_xor(s, 1); s += __shfl_xor(s, 2);
        s += __shfl_xor(s, 4); s += __shfl_xor(s, 8);
        if (r0 == 0){
          int row = dt*128 + wr*64 + m*16 + rg*4 + r;
          atomicAdd(&ksum[b*DIM + row], s);
        }
      }
  }
}

// kv partials: kvp[ksp][b][h][d] = sum over 512 l (no atomics, no LDS).
// grid (x = 2x2 tile, y = ksp 0..7, z = b)
__global__ __launch_bounds__(256) void kv_ker(const unsigned short* __restrict__ Vt, const unsigned short* __restrict__ Kt,
                                              float* __restrict__ kvp){
  int qd = blockIdx.x, mt = qd >> 1, nt = qd & 1;
  int ksp = blockIdx.y, b = blockIdx.z;
  int tid = threadIdx.x, lane = tid & 63, w = tid >> 6, wr = w >> 1, wc = w & 1;
  const unsigned short* A = Vt + (long)b*DIM*SEQ + (long)mt*128*SEQ;
  const unsigned short* B = Kt + (long)b*DIM*SEQ + (long)nt*128*SEQ;
  int l0 = ksp*(SEQ/NSPLIT);
  f32x4 acc[4][4] = {};
  #pragma unroll 4
  for (int ks = 0; ks < (SEQ/NSPLIT)/32; ks++){   // 16 iters
    int k0 = l0 + ks*32;
    bf16x8 af[4], bf[4];
    #pragma unroll
    for (int m = 0; m < 4; m++) af[m] = ldfrag_b(A, wr*64 + m*16, SEQ, k0, lane);
    #pragma unroll
    for (int n = 0; n < 4; n++) bf[n] = ldfrag_b(B, wc*64 + n*16, SEQ, k0, lane);
    #pragma unroll
    for (int m = 0; m < 4; m++)
      #pragma unroll
      for (int n = 0; n < 4; n++)
        acc[m][n] = __builtin_amdgcn_mfma_f32_16x16x32_bf16(af[m], bf[n], acc[m][n], 0, 0, 0);
  }
  int r0 = lane & 15, rg = lane >> 4;
  float* base = kvp + (long)(ksp*BATCH + b)*DIM*DIM;
  #pragma unroll
  for (int m = 0; m < 4; m++)
    #pragma unroll
    for (int n = 0; n < 4; n++)
      #pragma unroll
      for (int r = 0; r < 4; r++){
        int row = mt*128 + wr*64 + m*16 + rg*4 + r;   // h
        int col = nt*128 + wc*64 + n*16 + r0;         // d
        base[row*DIM + col] = acc[m][n][r];
      }
}

// kvb[b][h][d] (bf16) = sum of NSPLIT fp32 partials
__global__ __launch_bounds__(256) void kv_reduce(const float* __restrict__ kvp, unsigned short* __restrict__ kvb){
  int i = blockIdx.x*256 + threadIdx.x;   // 0 .. BATCH*65536-1
  int b = i >> 16, e = i & 65535;
  float s = 0.f;
  #pragma unroll
  for (int sp = 0; sp < NSPLIT; sp++) s += kvp[(long)(sp*BATCH + b)*65536 + e];
  kvb[i] = f2b(s);
}

// z[g] = dot(Q[g,:], ksum[b,:]) + 1e-6 ; one wave per row
__global__ __launch_bounds__(256) void zker(const unsigned short* __restrict__ Q, const float* __restrict__ ksum,
                                            float* __restrict__ z){
  int g = blockIdx.x*4 + (threadIdx.x >> 6);
  int lane = threadIdx.x & 63;
  int b = g >> 12;
  u16x4 qv = *(const u16x4*)(Q + (long)g*DIM + lane*4);
  const float* kp = ksum + b*DIM + lane*4;
  float s = b2f(qv[0])*kp[0] + b2f(qv[1])*kp[1] + b2f(qv[2])*kp[2] + b2f(qv[3])*kp[3];
  #pragma unroll
  for (int o = 1; o < 64; o <<= 1) s += __shfl_xor(s, o);
  if (lane == 0) z[g] = s + 1e-6f;
}

// out[g][h] = (sum_d Q[g][d]*kvb[h][d]) / z[g]   (fp32 out), no LDS
__global__ __launch_bounds__(256) void out_ker(const unsigned short* __restrict__ Q, const unsigned short* __restrict__ kvb,
                                               const float* __restrict__ z, float* __restrict__ out){
  int lt = blockIdx.x, ht = blockIdx.y, b = blockIdx.z;
  int tid = threadIdx.x, lane = tid & 63, w = tid >> 6, wr = w >> 1, wc = w & 1;
  const unsigned short* A = Q + ((long)b*SEQ + (long)lt*128)*DIM;
  const unsigned short* B = kvb + b*DIM*DIM + ht*128*DIM;
  f32x4 acc[4][4] = {};
  #pragma unroll
  for (int ks = 0; ks < 8; ks++){
    int k0 = ks*32;
    bf16x8 af[4], bf[4];
    #pragma unroll
    for (int m = 0; m < 4; m++) af[m] = ldfrag_b(A, wr*64 + m*16, DIM, k0, lane);
    #pragma unroll
    for (int n = 0; n < 4; n++) bf[n] = ldfrag_b(B, wc*64 + n*16, DIM, k0, lane);
    #pragma unroll
    for (int m = 0; m < 4; m++)
      #pragma unroll
      for (int n = 0; n < 4; n++)
        acc[m][n] = __builtin_amdgcn_mfma_f32_16x16x32_bf16(af[m], bf[n], acc[m][n], 0, 0, 0);
  }
  int r0 = lane & 15, rg = lane >> 4;
  #pragma unroll
  for (int m = 0; m < 4; m++)
    #pragma unroll
    for (int r = 0; r < 4; r++){
      long g = (long)b*SEQ + lt*128 + wr*64 + m*16 + rg*4 + r;
      float inv = 1.0f / z[g];
      #pragma unroll
      for (int n = 0; n < 4; n++){
        int col = ht*128 + wc*64 + n*16 + r0;
        out[g*DIM + col] = acc[m][n][r] * inv;
      }
    }
}

extern "C" void kernel_launch(void* const* d_in, const int* in_sizes, int n_in,
                              void* d_out, int out_size, void* d_ws, size_t ws_size,
                              hipStream_t stream){
  const float* q  = (const float*)d_in[0];
  const float* k  = (const float*)d_in[1];
  const float* v  = (const float*)d_in[2];
  const float* Wq = (const float*)d_in[3];
  const float* bq = (const float*)d_in[4];
  const float* Wk = (const float*)d_in[5];
  const float* bk = (const float*)d_in[6];
  const float* Wv = (const float*)d_in[7];
  const float* bv = (const float*)d_in[8];
  float* out = (float*)d_out;

  char* ws = (char*)d_ws;
  size_t off = 0;
  auto alloc = [&](size_t bytes){ void* p = ws + off; off += (bytes + 255) & ~(size_t)255; return p; };
  unsigned short* Q   = (unsigned short*)alloc((size_t)MTOT*DIM*2);          // 16 MiB
  unsigned short* Kt  = (unsigned short*)alloc((size_t)BATCH*DIM*SEQ*2);     // 16 MiB
  unsigned short* Vt  = (unsigned short*)alloc((size_t)BATCH*DIM*SEQ*2);     // 16 MiB
  unsigned short* Wt  = (unsigned short*)alloc((size_t)3*DIM*DIM*2);         // 384 KiB
  float*          kvp = (float*)alloc((size_t)NSPLIT*BATCH*DIM*DIM*4);       // 16 MiB
  unsigned short* kvb = (unsigned short*)alloc((size_t)BATCH*DIM*DIM*2);     // 1 MiB
  float*          ksum= (float*)alloc((size_t)BATCH*DIM*4);                  // 8 KiB
  float*          zb  = (float*)alloc((size_t)MTOT*4);                       // 128 KiB

  hipMemsetAsync(ksum, 0, (size_t)BATCH*DIM*4, stream);   // only remaining atomic target

  hipLaunchKernelGGL(prep_wt,     dim3(768),        dim3(256), 0, stream, Wq, Wk, Wv, Wt);
  hipLaunchKernelGGL(proj_all_ker,dim3(32,2,24),    dim3(256), 0, stream, q, k, v, Wt, bq, bk, bv, Q, Kt, Vt, ksum);
  hipLaunchKernelGGL(kv_ker,      dim3(4,NSPLIT,8), dim3(256), 0, stream, Vt, Kt, kvp);
  hipLaunchKernelGGL(kv_reduce,   dim3(2048),       dim3(256), 0, stream, kvp, kvb);
  hipLaunchKernelGGL(zker,        dim3(8192),       dim3(256), 0, stream, Q, ksum, zb);
  hipLaunchKernelGGL(out_ker,     dim3(32,2,8),     dim3(256), 0, stream, Q, kvb, zb, out);
}

// Round 10
// 249.833 us; speedup vs baseline: 1.1173x; 1.1173x over previous
//
#include <hip/hip_runtime.h>
#include <hip/hip_bf16.h>
#include <math.h>

#define DIM 256
#define BATCH 8
#define SEQ 4096
#define MTOT (BATCH*SEQ)
#define NSPLIT 8   // kv split-K factor (512 l per split)

typedef __attribute__((ext_vector_type(8))) short bf16x8;
typedef __attribute__((ext_vector_type(4))) float f32x4;
typedef __attribute__((ext_vector_type(8))) unsigned short u16x8;
typedef __attribute__((ext_vector_type(4))) unsigned short u16x4;

__device__ inline unsigned short f2b(float f){
  unsigned int u = __float_as_uint(f);
  u = u + 0x7FFFu + ((u >> 16) & 1u);   // RNE
  return (unsigned short)(u >> 16);
}
__device__ inline float b2f(unsigned short h){
  return __uint_as_float(((unsigned int)h) << 16);
}

// ---------------------------------------------------------------------------
// Async global->LDS staging (global_load_lds width=16).
// LDS dest is wave-uniform base + lane*16 (HW); swizzle is applied on the
// per-lane GLOBAL source address and undone on the ds_read side (rule #21).
// bf16 tile [R][64] (128B rows): LDS[row][s] = G[row][s ^ (row&7)],  s=0..7
// fp32 tile [R][64] (256B rows): LDS[row][s] = G[row][s ^ (row&15)], s=0..15
// Read-side bank math: 16 lanes (rows r0..r0+15) at fixed slot j hit slots
// j^(row&7 or 15) -> >=8 distinct 16B slots -> <=2 lanes/bank = free (m136).
// ---------------------------------------------------------------------------
__device__ __forceinline__ void gl2lds16(const void* g, void* l){
  __builtin_amdgcn_global_load_lds(
      (const __attribute__((address_space(1))) void*)g,
      (__attribute__((address_space(3))) void*)l, 16, 0, 0);
}

template<int R>
__device__ __forceinline__ void stage_b16(const unsigned short* g, int ld, void* lds, int tid){
  int lane = tid & 63;
  #pragma unroll
  for (int i = 0; i < R/32; i++){
    int c = (tid >> 6)*(R/32) + i;          // 1KB chunk = 8 rows
    int row = c*8 + (lane >> 3);
    int s = lane & 7;
    gl2lds16((const char*)(g + (long)row*ld) + ((s ^ (row & 7)) << 4),
             (char*)lds + c*1024);
  }
}
template<int R>
__device__ __forceinline__ void stage_f32(const float* g, int ld, void* lds, int tid){
  int lane = tid & 63;
  #pragma unroll
  for (int i = 0; i < R/16; i++){
    int c = (tid >> 6)*(R/16) + i;          // 1KB chunk = 4 rows
    int row = c*4 + (lane >> 4);
    int s = lane & 15;
    gl2lds16((const char*)(g + (long)row*ld) + ((s ^ (row & 15)) << 4),
             (char*)lds + c*1024);
  }
}

// frag readers (undo swizzle). mfma 16x16x32 frag: row=lane&15, k=(lane>>4)*8+j.
__device__ __forceinline__ bf16x8 rdfrag_b(const void* lds, int row0, int kk, int lane){
  int row = row0 + (lane & 15);
  int s = (kk*4 + (lane >> 4)) ^ (row & 7);
  return *(const bf16x8*)((const char*)lds + row*128 + s*16);
}
__device__ __forceinline__ bf16x8 rdfrag_f(const void* lds, int row0, int kk, int lane){
  int row = row0 + (lane & 15);
  int s0 = kk*8 + ((lane >> 4) << 1);
  const char* rp = (const char*)lds + row*256;
  f32x4 lo = *(const f32x4*)(rp + ((s0       ^ (row & 15)) << 4));
  f32x4 hi = *(const f32x4*)(rp + (((s0 + 1) ^ (row & 15)) << 4));
  bf16x8 r;
  r[0]=(short)f2b(lo[0]); r[1]=(short)f2b(lo[1]); r[2]=(short)f2b(lo[2]); r[3]=(short)f2b(lo[3]);
  r[4]=(short)f2b(hi[0]); r[5]=(short)f2b(hi[1]); r[6]=(short)f2b(hi[2]); r[7]=(short)f2b(hi[3]);
  return r;
}

// One BK=64 step on a 128x64 output tile: 4 waves as 2(wr)x2(wc); wave = 64x32.
template<bool AF32, bool BF32>
__device__ __forceinline__ void mma64(const void* lA, const void* lB, int lane,
                                      int wr, int wc, f32x4 acc[4][2]){
  #pragma unroll
  for (int kk = 0; kk < 2; kk++){
    bf16x8 af[4], bf[2];
    #pragma unroll
    for (int m = 0; m < 4; m++){
      if constexpr (AF32) af[m] = rdfrag_f(lA, wr*64 + m*16, kk, lane);
      else                af[m] = rdfrag_b(lA, wr*64 + m*16, kk, lane);
    }
    #pragma unroll
    for (int n = 0; n < 2; n++){
      if constexpr (BF32) bf[n] = rdfrag_f(lB, wc*32 + n*16, kk, lane);
      else                bf[n] = rdfrag_b(lB, wc*32 + n*16, kk, lane);
    }
    #pragma unroll
    for (int m = 0; m < 4; m++)
      #pragma unroll
      for (int n = 0; n < 2; n++)
        acc[m][n] = __builtin_amdgcn_mfma_f32_16x16x32_bf16(af[m], bf[n], acc[m][n], 0, 0, 0);
  }
}

// Wt[s][n][k] = Ws[k][n]  (bf16, B^T layout; s: 0=Wq 1=Wk 2=Wv)
__global__ __launch_bounds__(256) void prep_wt(const float* __restrict__ Wq, const float* __restrict__ Wk,
                                               const float* __restrict__ Wv, unsigned short* __restrict__ Wt){
  int i = blockIdx.x*256 + threadIdx.x;
  int s = i >> 16, r = i & 65535, n = r & 255, kk = r >> 8;
  const float* W = (s == 0) ? Wq : ((s == 1) ? Wk : Wv);
  Wt[s*65536 + n*256 + kk] = f2b(W[kk*256 + n]);
}

// K/V projections, transposed output: Yt[d][l] = feat?(sum_k W[k][d]*X[l][k] + b[d])
// grid (lt 0..63, dt 0..1, z 0..15): sv = z&1 (0=K feat+ksum, 1=V), b = z>>1.
// A = Wt_s rows d [128][64k] bf16; B = X rows l [64][64k] fp32.
__global__ __launch_bounds__(256) void proj_kv_ker(const float* __restrict__ kin, const float* __restrict__ vin,
                                                   const unsigned short* __restrict__ Wt,
                                                   const float* __restrict__ bkp, const float* __restrict__ bvp,
                                                   unsigned short* __restrict__ Kt, unsigned short* __restrict__ Vt,
                                                   float* __restrict__ ksum){
  __shared__ __align__(1024) char smem[32*1024];   // [0,16K)=A bf16, [16K,32K)=B f32; epilogue reuses [0,16K) as ldsT
  int lt = blockIdx.x, dt = blockIdx.y;
  int z = blockIdx.z, sv = z & 1, b = z >> 1;
  int tid = threadIdx.x, lane = tid & 63, w = tid >> 6, wr = w >> 1, wc = w & 1;
  const float* X = (sv ? vin : kin) + ((long)b*SEQ + (long)lt*64)*DIM;
  const unsigned short* Wb = Wt + (sv ? 2 : 1)*65536 + dt*128*256;
  const float* bias = sv ? bvp : bkp;
  void* lA = smem; void* lB = smem + 16*1024;

  f32x4 acc[4][2] = {};
  for (int kt = 0; kt < 4; kt++){
    __syncthreads();
    stage_b16<128>(Wb + kt*64, 256, lA, tid);
    stage_f32<64>(X + kt*64, DIM, lB, tid);
    __syncthreads();                                 // drains vmcnt -> data in LDS
    mma64<false, true>(lA, lB, lane, wr, wc, acc);
  }

  int r0 = lane & 15, rg = lane >> 4;
  unsigned short* ldsT = (unsigned short*)smem;       // [128 d][64 l]
  float sums[4][4];
  #pragma unroll
  for (int m = 0; m < 4; m++) for (int r = 0; r < 4; r++) sums[m][r] = 0.f;
  __syncthreads();                                    // all waves done reading lA/lB
  #pragma unroll
  for (int m = 0; m < 4; m++)
    #pragma unroll
    for (int r = 0; r < 4; r++){
      int dl = wr*64 + m*16 + rg*4 + r;
      float bvv = bias[dt*128 + dl];
      #pragma unroll
      for (int n = 0; n < 2; n++){
        int ll = wc*32 + n*16 + r0;
        float vv = acc[m][n][r] + bvv;
        if (!sv) vv = vv > 0.f ? vv + 1.f : expf(vv);  // elu+1
        ldsT[dl*64 + ll] = f2b(vv);
        sums[m][r] += vv;
      }
    }
  __syncthreads();
  unsigned short* Yt = (sv ? Vt : Kt) + (long)b*DIM*SEQ;
  {
    int row = tid >> 1, hf = tid & 1;                 // 128 rows x 2 halves of 64B
    const unsigned short* sp = ldsT + row*64 + hf*32;
    unsigned short* dp = Yt + (long)(dt*128 + row)*SEQ + lt*64 + hf*32;
    #pragma unroll
    for (int j = 0; j < 4; j++) *(u16x8*)(dp + j*8) = *(const u16x8*)(sp + j*8);
  }
  if (!sv){
    #pragma unroll
    for (int m = 0; m < 4; m++)
      #pragma unroll
      for (int r = 0; r < 4; r++){
        float s = sums[m][r];
        s += __shfl_xor(s, 1); s += __shfl_xor(s, 2);
        s += __shfl_xor(s, 4); s += __shfl_xor(s, 8);
        if (r0 == 0){
          int dl = wr*64 + m*16 + rg*4 + r;
          atomicAdd(&ksum[b*DIM + dt*128 + dl], s);
        }
      }
  }
}

// Q projection, natural output: Q[l][d] = feat(sum_k X[l][k]*Wq[k][d] + b[d])
// grid (lt 0..31, dt 0..3, b 0..7). A = X rows l [128][64k] fp32; B = Wq rows d [64][64k] bf16.
__global__ __launch_bounds__(256) void proj_q_ker(const float* __restrict__ qin,
                                                  const unsigned short* __restrict__ Wt,
                                                  const float* __restrict__ bqp,
                                                  unsigned short* __restrict__ Qo){
  __shared__ __align__(1024) char smem[40*1024];   // [0,32K)=A f32, [32K,40K)=B bf16; ldsT reuses [0,16K)
  int lt = blockIdx.x, dt = blockIdx.y, b = blockIdx.z;
  int tid = threadIdx.x, lane = tid & 63, w = tid >> 6, wr = w >> 1, wc = w & 1;
  const float* X = qin + ((long)b*SEQ + (long)lt*128)*DIM;
  const unsigned short* Wb = Wt + dt*64*256;       // Wq at s=0
  void* lA = smem; void* lB = smem + 32*1024;

  f32x4 acc[4][2] = {};
  for (int kt = 0; kt < 4; kt++){
    __syncthreads();
    stage_f32<128>(X + kt*64, DIM, lA, tid);
    stage_b16<64>(Wb + kt*64, 256, lB, tid);
    __syncthreads();
    mma64<true, false>(lA, lB, lane, wr, wc, acc);
  }

  int r0 = lane & 15, rg = lane >> 4;
  unsigned short* ldsT = (unsigned short*)smem;    // [128 l][64 d]
  __syncthreads();
  #pragma unroll
  for (int n = 0; n < 2; n++){
    int dl = wc*32 + n*16 + r0;
    float bvv = bqp[dt*64 + dl];
    #pragma unroll
    for (int m = 0; m < 4; m++)
      #pragma unroll
      for (int r = 0; r < 4; r++){
        int ll = wr*64 + m*16 + rg*4 + r;
        float vv = acc[m][n][r] + bvv;
        vv = vv > 0.f ? vv + 1.f : expf(vv);        // elu+1
        ldsT[ll*64 + dl] = f2b(vv);
      }
  }
  __syncthreads();
  {
    int row = tid >> 1, hf = tid & 1;
    const unsigned short* sp = ldsT + row*64 + hf*32;
    unsigned short* dp = Qo + ((long)b*SEQ + lt*128 + row)*DIM + dt*64 + hf*32;
    #pragma unroll
    for (int j = 0; j < 4; j++) *(u16x8*)(dp + j*8) = *(const u16x8*)(sp + j*8);
  }
}

// kv partials: kvp[ksp][b][h][d] over 512 l each. 128(h)x64(d) tiles.
// grid (x 0..7: mt=x>>2, nt=x&3; ksp 0..7; b 0..7) = 512 blocks.
__global__ __launch_bounds__(256) void kv_ker(const unsigned short* __restrict__ Vt, const unsigned short* __restrict__ Kt,
                                              float* __restrict__ kvp){
  __shared__ __align__(1024) char smem[24*1024];   // A Vt [128][64] 16K; B Kt [64][64] 8K
  int x = blockIdx.x, mt = x >> 2, nt = x & 3;
  int ksp = blockIdx.y, b = blockIdx.z;
  int tid = threadIdx.x, lane = tid & 63, w = tid >> 6, wr = w >> 1, wc = w & 1;
  const unsigned short* A = Vt + (long)b*DIM*SEQ + (long)mt*128*SEQ + ksp*512;
  const unsigned short* B = Kt + (long)b*DIM*SEQ + (long)nt*64*SEQ  + ksp*512;
  void* lA = smem; void* lB = smem + 16*1024;

  f32x4 acc[4][2] = {};
  for (int kt = 0; kt < 8; kt++){
    __syncthreads();
    stage_b16<128>(A + kt*64, SEQ, lA, tid);
    stage_b16<64>(B + kt*64, SEQ, lB, tid);
    __syncthreads();
    mma64<false, false>(lA, lB, lane, wr, wc, acc);
  }
  int r0 = lane & 15, rg = lane >> 4;
  float* base = kvp + (long)(ksp*BATCH + b)*DIM*DIM;
  #pragma unroll
  for (int m = 0; m < 4; m++)
    #pragma unroll
    for (int r = 0; r < 4; r++){
      int h = mt*128 + wr*64 + m*16 + rg*4 + r;
      #pragma unroll
      for (int n = 0; n < 2; n++){
        int d = nt*64 + wc*32 + n*16 + r0;
        base[h*DIM + d] = acc[m][n][r];
      }
    }
}

// kvb[b][h][d] (bf16) = sum of NSPLIT fp32 partials
__global__ __launch_bounds__(256) void kv_reduce(const float* __restrict__ kvp, unsigned short* __restrict__ kvb){
  int i = blockIdx.x*256 + threadIdx.x;
  int b = i >> 16, e = i & 65535;
  float s = 0.f;
  #pragma unroll
  for (int sp = 0; sp < NSPLIT; sp++) s += kvp[(long)(sp*BATCH + b)*65536 + e];
  kvb[i] = f2b(s);
}

// z[g] = dot(Q[g,:], ksum[b,:]) + 1e-6 ; one wave per row
__global__ __launch_bounds__(256) void zker(const unsigned short* __restrict__ Q, const float* __restrict__ ksum,
                                            float* __restrict__ z){
  int g = blockIdx.x*4 + (threadIdx.x >> 6);
  int lane = threadIdx.x & 63;
  int b = g >> 12;
  u16x4 qv = *(const u16x4*)(Q + (long)g*DIM + lane*4);
  const float* kp = ksum + b*DIM + lane*4;
  float s = b2f(qv[0])*kp[0] + b2f(qv[1])*kp[1] + b2f(qv[2])*kp[2] + b2f(qv[3])*kp[3];
  #pragma unroll
  for (int o = 1; o < 64; o <<= 1) s += __shfl_xor(s, o);
  if (lane == 0) z[g] = s + 1e-6f;
}

// out[g][h] = (sum_d Q[g][d]*kvb[h][d]) / z[g]. 128(l)x64(h) tiles.
// grid (lt 0..31, ht 0..3, b 0..7) = 1024 blocks.
__global__ __launch_bounds__(256) void out_ker(const unsigned short* __restrict__ Q, const unsigned short* __restrict__ kvb,
                                               const float* __restrict__ z, float* __restrict__ out){
  __shared__ __align__(1024) char smem[24*1024];
  int lt = blockIdx.x, ht = blockIdx.y, b = blockIdx.z;
  int tid = threadIdx.x, lane = tid & 63, w = tid >> 6, wr = w >> 1, wc = w & 1;
  const unsigned short* A = Q + ((long)b*SEQ + (long)lt*128)*DIM;
  const unsigned short* B = kvb + b*65536 + ht*64*DIM;
  void* lA = smem; void* lB = smem + 16*1024;

  f32x4 acc[4][2] = {};
  for (int kt = 0; kt < 4; kt++){
    __syncthreads();
    stage_b16<128>(A + kt*64, DIM, lA, tid);
    stage_b16<64>(B + kt*64, DIM, lB, tid);
    __syncthreads();
    mma64<false, false>(lA, lB, lane, wr, wc, acc);
  }
  int r0 = lane & 15, rg = lane >> 4;
  #pragma unroll
  for (int m = 0; m < 4; m++)
    #pragma unroll
    for (int r = 0; r < 4; r++){
      long g = (long)b*SEQ + lt*128 + wr*64 + m*16 + rg*4 + r;
      float inv = 1.0f / z[g];
      #pragma unroll
      for (int n = 0; n < 2; n++){
        int col = ht*64 + wc*32 + n*16 + r0;
        out[g*DIM + col] = acc[m][n][r] * inv;
      }
    }
}

extern "C" void kernel_launch(void* const* d_in, const int* in_sizes, int n_in,
                              void* d_out, int out_size, void* d_ws, size_t ws_size,
                              hipStream_t stream){
  const float* q  = (const float*)d_in[0];
  const float* k  = (const float*)d_in[1];
  const float* v  = (const float*)d_in[2];
  const float* Wq = (const float*)d_in[3];
  const float* bq = (const float*)d_in[4];
  const float* Wk = (const float*)d_in[5];
  const float* bk = (const float*)d_in[6];
  const float* Wv = (const float*)d_in[7];
  const float* bv = (const float*)d_in[8];
  float* out = (float*)d_out;

  char* ws = (char*)d_ws;
  size_t off = 0;
  auto alloc = [&](size_t bytes){ void* p = ws + off; off += (bytes + 255) & ~(size_t)255; return p; };
  unsigned short* Q   = (unsigned short*)alloc((size_t)MTOT*DIM*2);          // 16 MiB
  unsigned short* Kt  = (unsigned short*)alloc((size_t)BATCH*DIM*SEQ*2);     // 16 MiB
  unsigned short* Vt  = (unsigned short*)alloc((size_t)BATCH*DIM*SEQ*2);     // 16 MiB
  unsigned short* Wt  = (unsigned short*)alloc((size_t)3*DIM*DIM*2);         // 384 KiB
  float*          kvp = (float*)alloc((size_t)NSPLIT*BATCH*DIM*DIM*4);       // 16 MiB
  unsigned short* kvb = (unsigned short*)alloc((size_t)BATCH*DIM*DIM*2);     // 1 MiB
  float*          ksum= (float*)alloc((size_t)BATCH*DIM*4);                  // 8 KiB
  float*          zb  = (float*)alloc((size_t)MTOT*4);                       // 128 KiB

  hipMemsetAsync(ksum, 0, (size_t)BATCH*DIM*4, stream);

  hipLaunchKernelGGL(prep_wt,    dim3(768),      dim3(256), 0, stream, Wq, Wk, Wv, Wt);
  hipLaunchKernelGGL(proj_kv_ker,dim3(64,2,16),  dim3(256), 0, stream, k, v, Wt, bk, bv, Kt, Vt, ksum);
  hipLaunchKernelGGL(proj_q_ker, dim3(32,4,8),   dim3(256), 0, stream, q, Wt, bq, Q);
  hipLaunchKernelGGL(kv_ker,     dim3(8,NSPLIT,8),dim3(256), 0, stream, Vt, Kt, kvp);
  hipLaunchKernelGGL(kv_reduce,  dim3(2048),     dim3(256), 0, stream, kvp, kvb);
  hipLaunchKernelGGL(zker,       dim3(8192),     dim3(256), 0, stream, Q, ksum, zb);
  hipLaunchKernelGGL(out_ker,    dim3(32,4,8),   dim3(256), 0, stream, Q, kvb, zb, out);
}